// Round 6
// baseline (1444.786 us; speedup 1.0000x reference)
//
#include <hip/hip_runtime.h>
#include <math.h>

#define NN 50000
#define DD 128
#define HH 4
#define DHH 32
#define EE 600000
#define N2 (2*NN)

typedef unsigned short u16;
typedef unsigned int   u32;

__device__ __forceinline__ float lrelu(float v){ return v > 0.f ? v : 0.2f*v; }
__device__ __forceinline__ float gelu_exact(float x){ return 0.5f*x*(1.f+erff(x*0.70710678118654752f)); }
__device__ __forceinline__ u16 f2bf(float f){
  u32 u = __float_as_uint(f);
  u32 r = (u + 0x7fffu + ((u>>16)&1u)) >> 16;
  return (u16)r;
}
__device__ __forceinline__ u32 pack2bf(float a, float b){ return (u32)f2bf(a) | ((u32)f2bf(b)<<16); }
__device__ __forceinline__ float bflo(u32 u){ return __uint_as_float(u<<16); }
__device__ __forceinline__ float bfhi(u32 u){ return __uint_as_float(u & 0xffff0000u); }

// ---------------- FiLM (tiny) ----------------
__global__ void film_kernel(const float* __restrict__ z, const float* __restrict__ W1, const float* __restrict__ b1,
                            const float* __restrict__ W2, const float* __restrict__ b2, float* __restrict__ gb){
  __shared__ float hsh[256];
  int j = threadIdx.x;
  float acc = b1[j];
  for(int d=0; d<DD; ++d) acc = fmaf(z[d], W1[d*256+j], acc);
  hsh[j] = gelu_exact(acc);
  __syncthreads();
  float acc2 = b2[j];
  for(int k=0;k<256;++k) acc2 = fmaf(hsh[k], W2[k*256+j], acc2);
  gb[j] = acc2;
}

// ---------------- CSR build (joint over both edge types) ----------------
__global__ void count2_kernel(const int* __restrict__ d0, const int* __restrict__ d1, int* __restrict__ jcnt){
  int e = blockIdx.x*blockDim.x+threadIdx.x;
  if(e < EE)        atomicAdd(&jcnt[d0[e]], 1);
  else if(e < 2*EE) atomicAdd(&jcnt[NN + d1[e-EE]], 1);
}

__global__ void scan_partial(const int* __restrict__ cnt, int* __restrict__ bsum){
  int t = threadIdx.x;
  int i0 = blockIdx.x*512 + 2*t;
  int s = 0;
  if(i0   < N2) s += cnt[i0];
  if(i0+1 < N2) s += cnt[i0+1];
  __shared__ int red[256];
  red[t]=s; __syncthreads();
  for(int off=128; off>0; off>>=1){ if(t<off) red[t]+=red[t+off]; __syncthreads(); }
  if(t==0) bsum[blockIdx.x]=red[0];
}

__global__ void scan_blocksums(const int* __restrict__ bsum, int* __restrict__ bofs, int* __restrict__ jrs_last, int nb){
  __shared__ int sh[256];
  int t = threadIdx.x;
  int v = (t<nb)? bsum[t] : 0;
  sh[t]=v; __syncthreads();
  for(int off=1; off<256; off<<=1){
    int u = (t>=off)? sh[t-off] : 0; __syncthreads();
    sh[t]+=u; __syncthreads();
  }
  if(t<nb) bofs[t] = sh[t]-v;
  if(t==nb-1) *jrs_last = sh[t];
}

__global__ void scan_final(const int* __restrict__ cnt, const int* __restrict__ bofs,
                           int* __restrict__ jrs, int* __restrict__ jcur){
  int t = threadIdx.x;
  int i0 = blockIdx.x*512 + 2*t;
  int a = (i0   < N2)? cnt[i0]   : 0;
  int c = (i0+1 < N2)? cnt[i0+1] : 0;
  int s = a+c;
  __shared__ int sh[256];
  sh[t]=s; __syncthreads();
  for(int off=1; off<256; off<<=1){
    int u = (t>=off)? sh[t-off] : 0; __syncthreads();
    sh[t]+=u; __syncthreads();
  }
  int ex = bofs[blockIdx.x] + sh[t]-s;
  if(i0   < N2){ jrs[i0]=ex;     jcur[i0]=ex; }
  if(i0+1 < N2){ jrs[i0+1]=ex+a; jcur[i0+1]=ex+a; }
}

__global__ void fill2_kernel(const int* __restrict__ ei0, const int* __restrict__ ei1,
                             int* __restrict__ jcur, u16* __restrict__ es){
  int e = blockIdx.x*blockDim.x+threadIdx.x;
  if(e < EE){
    int d = ei0[EE+e];
    int pos = atomicAdd(&jcur[d],1);
    es[pos] = (u16)ei0[e];
  } else if(e < 2*EE){
    int i = e-EE;
    int d = ei1[EE+i];
    int pos = atomicAdd(&jcur[NN+d],1);
    es[pos] = (u16)ei1[i];
  }
}

// ---------------- GEMM: C[n,128] = A[n,128] @ W[128,128] + fused epilogues ----------------
constexpr int GM_BIAS   = 1;   // + bias[c]
constexpr int GM_FILM   = 4;   // o += base[row,c]; o = fgb[c]*o + fgb[128+c]
constexpr int GM_BF16   = 8;   // bf16 output
constexpr int GM_SKIP   = 16;  // o = sk*o + (1-sk)*base[row,c], sk=sigmoid(skipv[0])
constexpr int GM_ATT    = 64;  // GAT logits from accumulators: bias=a_s, bias2=a_d -> als8/ald8 (stride 8)

template<int MODE>
__global__ __launch_bounds__(256) void gemm(const float* __restrict__ Av, const float* __restrict__ Wg,
    const float* __restrict__ bias, const float* __restrict__ bias2,
    const float* __restrict__ base, const float* __restrict__ fgb, const float* __restrict__ skipv,
    float* __restrict__ als, float* __restrict__ ald,
    void* __restrict__ Cv, int n){
  __shared__ float As[32][128];
  const int tid = threadIdx.x;
  const int row0 = blockIdx.x*32;
  {
    const float4* Ag = (const float4*)(Av + (size_t)row0*DD);
    const int maxv = (min(32, n-row0))*32;
    #pragma unroll
    for(int j=0;j<4;++j){
      int v = tid + j*256;
      float4 val = make_float4(0.f,0.f,0.f,0.f);
      if(v < maxv) val = Ag[v];
      ((float4*)&As[0][0])[v] = val;
    }
  }
  __syncthreads();
  const int c2 = tid & 63;
  const int rh = tid >> 6;
  float acc[8][2];
  #pragma unroll
  for(int r=0;r<8;++r){ acc[r][0]=0.f; acc[r][1]=0.f; }
  #pragma unroll 8
  for(int k=0;k<128;++k){
    const float2 w = *(const float2*)&Wg[(size_t)k*128 + 2*c2];
    #pragma unroll
    for(int r=0;r<8;++r){
      const float a = As[rh*8+r][k];
      acc[r][0] = fmaf(a, w.x, acc[r][0]);
      acc[r][1] = fmaf(a, w.y, acc[r][1]);
    }
  }
  const int c = 2*c2;
  if(MODE & GM_ATT){
    const float2 asv = *(const float2*)&bias[c];   // a_s folded over columns of this head
    const float2 adv = *(const float2*)&bias2[c];  // a_d
    const int h = c2 >> 4;
    #pragma unroll
    for(int r=0;r<8;++r){
      float ps = asv.x*acc[r][0] + asv.y*acc[r][1];
      float pd = adv.x*acc[r][0] + adv.y*acc[r][1];
      ps += __shfl_xor(ps,1); ps += __shfl_xor(ps,2); ps += __shfl_xor(ps,4); ps += __shfl_xor(ps,8);
      pd += __shfl_xor(pd,1); pd += __shfl_xor(pd,2); pd += __shfl_xor(pd,4); pd += __shfl_xor(pd,8);
      const int row = row0 + rh*8 + r;
      if(row < n && (tid&15)==0){ als[(size_t)row*8 + 2*h] = ps; ald[(size_t)row*8 + 2*h] = pd; }
    }
  }
  float b0=0.f, b1=0.f;
  if(MODE & GM_BIAS){ b0 += bias[c]; b1 += bias[c+1]; }
  float sk = 0.f;
  if(MODE & GM_SKIP) sk = 1.f/(1.f+__expf(-skipv[0]));
  #pragma unroll
  for(int r=0;r<8;++r){
    int row = row0 + rh*8 + r;
    if(row < n){
      float o0 = acc[r][0]+b0, o1 = acc[r][1]+b1;
      if(MODE & GM_SKIP){
        o0 = sk*o0 + (1.f-sk)*base[(size_t)row*DD + c];
        o1 = sk*o1 + (1.f-sk)*base[(size_t)row*DD + c + 1];
      }
      if(MODE & GM_FILM){
        o0 += base[(size_t)row*DD + c];
        o1 += base[(size_t)row*DD + c + 1];
        o0 = fgb[c]*o0 + fgb[128+c];
        o1 = fgb[c+1]*o1 + fgb[128+c+1];
      }
      if(MODE & GM_BF16){
        ((u32*)&((u16*)Cv)[(size_t)row*DD + c])[0] = pack2bf(o0, o1);
      } else {
        float* C = (float*)Cv;
        C[(size_t)row*DD + c]   = o0;
        C[(size_t)row*DD + c+1] = o1;
      }
    }
  }
}

// ---------------- GAT merged gather: both types, per-type xp tables ----------------
// out[node][f] = b0[f]+b1[f] + sum_t (softmax_t-weighted sum of xp_t[src][f]); f=2*lane, head=f>>5
__global__ __launch_bounds__(256) void gat_gather3(const u16* __restrict__ xp0, const u16* __restrict__ xp1,
    const float* __restrict__ als8, const float* __restrict__ ald8,
    const int* __restrict__ jrs, const u16* __restrict__ es,
    const float* __restrict__ gb0, const float* __restrict__ gb1, float* __restrict__ out){
  const int gid = blockIdx.x*blockDim.x + threadIdx.x;
  const int node = gid >> 6;
  const int lane = threadIdx.x & 63;
  if(node >= NN) return;
  const int h = lane >> 4;
  const int cc = 2*lane;
  float o0 = gb0[cc] + gb1[cc], o1 = gb0[cc+1] + gb1[cc+1];
  #pragma unroll
  for(int t=0;t<2;++t){
    const u16* __restrict__ xp = t ? xp1 : xp0;
    const float aldv = ald8[(size_t)node*8 + 2*h + t];
    const int s0 = jrs[t*NN+node], s1 = jrs[t*NN+node+1];
    float ssum=0.f, a0=0.f, a1=0.f;
    int p = s0;
    for(; p+3<s1; p+=4){
      const int sA = es[p], sB = es[p+1], sC = es[p+2], sD = es[p+3];
      const u32 xA = *(const u32*)&xp[(size_t)sA*DD + cc];
      const u32 xB = *(const u32*)&xp[(size_t)sB*DD + cc];
      const u32 xC = *(const u32*)&xp[(size_t)sC*DD + cc];
      const u32 xD = *(const u32*)&xp[(size_t)sD*DD + cc];
      float lA = als8[(size_t)sA*8 + 2*h + t] + aldv; lA = lA>0.f? lA : 0.2f*lA;
      float lB = als8[(size_t)sB*8 + 2*h + t] + aldv; lB = lB>0.f? lB : 0.2f*lB;
      float lC = als8[(size_t)sC*8 + 2*h + t] + aldv; lC = lC>0.f? lC : 0.2f*lC;
      float lD = als8[(size_t)sD*8 + 2*h + t] + aldv; lD = lD>0.f? lD : 0.2f*lD;
      const float eA=__expf(lA), eB=__expf(lB), eC=__expf(lC), eD=__expf(lD);
      ssum += (eA+eB)+(eC+eD);
      a0 = fmaf(eA, bflo(xA), a0); a1 = fmaf(eA, bfhi(xA), a1);
      a0 = fmaf(eB, bflo(xB), a0); a1 = fmaf(eB, bfhi(xB), a1);
      a0 = fmaf(eC, bflo(xC), a0); a1 = fmaf(eC, bfhi(xC), a1);
      a0 = fmaf(eD, bflo(xD), a0); a1 = fmaf(eD, bfhi(xD), a1);
    }
    for(; p<s1; ++p){
      const int sA = es[p];
      const u32 xA = *(const u32*)&xp[(size_t)sA*DD + cc];
      float lA = als8[(size_t)sA*8 + 2*h + t] + aldv; lA = lA>0.f? lA : 0.2f*lA;
      const float eA = __expf(lA);
      ssum += eA;
      a0 = fmaf(eA, bflo(xA), a0); a1 = fmaf(eA, bfhi(xA), a1);
    }
    { // self loop (appended in reference)
      float lg = als8[(size_t)node*8 + 2*h + t] + aldv;
      lg = lg>0.f? lg : 0.2f*lg;
      const float ev = __expf(lg);
      ssum += ev;
      const u32 xr = *(const u32*)&xp[(size_t)node*DD + cc];
      a0 = fmaf(ev, bflo(xr), a0); a1 = fmaf(ev, bfhi(xr), a1);
    }
    const float inv = 1.f/ssum;
    o0 = fmaf(a0, inv, o0); o1 = fmaf(a1, inv, o1);
  }
  *(float2*)&out[(size_t)node*DD + cc] = make_float2(o0, o1);
}

// ---------------- BN (deterministic two-stage) ----------------
__global__ void bn_stats(const float* __restrict__ X, float* __restrict__ part){
  int f = threadIdx.x & 127, rg = threadIdx.x>>7;
  float s=0.f, s2=0.f;
  for(int r = blockIdx.x*2+rg; r<NN; r += gridDim.x*2){
    float v = X[(size_t)r*DD+f]; s+=v; s2 = fmaf(v,v,s2);
  }
  __shared__ float ls[256], ls2[256];
  ls[threadIdx.x]=s; ls2[threadIdx.x]=s2; __syncthreads();
  if(rg==0){
    part[blockIdx.x*256 + f]       = ls[f]+ls[128+f];
    part[blockIdx.x*256 + 128 + f] = ls2[f]+ls2[128+f];
  }
}

__global__ void bn_finalize(const float* __restrict__ part, const float* __restrict__ gamma,
                            const float* __restrict__ beta, float* __restrict__ stat, int nblk){
  int f=threadIdx.x;
  float s=0.f, s2=0.f;
  for(int b=0;b<nblk;++b){ s+=part[b*256+f]; s2+=part[b*256+128+f]; }
  float mu = s/(float)NN;
  float var = s2/(float)NN - mu*mu;
  float rs = rsqrtf(var+1e-5f);
  stat[f]     = gamma[f]*rs;
  stat[128+f] = beta[f] - gamma[f]*rs*mu;
}

// out = lrelu(xprev + A*acc + B)
__global__ void bn_apply_lrelu(const float* __restrict__ xprev, const float* __restrict__ acc,
                               const float* __restrict__ stat, float* __restrict__ out){
  int idx = blockIdx.x*blockDim.x+threadIdx.x;
  if(idx >= NN*64) return;
  int c = (2*idx) & 127;
  float2 x = ((const float2*)xprev)[idx];
  float2 a = ((const float2*)acc)[idx];
  float o0 = lrelu(x.x + fmaf(stat[c],   a.x, stat[128+c]));
  float o1 = lrelu(x.y + fmaf(stat[c+1], a.y, stat[128+c+1]));
  ((float2*)out)[idx] = make_float2(o0,o1);
}

// ---------------- HGT merged edge kernel (both types, shared k/v tables) ----------------
__global__ __launch_bounds__(256) void hgt_merged_kernel(const float* __restrict__ q,
    const u16* __restrict__ ktb, const u16* __restrict__ vtb,
    const int* __restrict__ jrs, const u16* __restrict__ es,
    const float* __restrict__ a_rel, const float* __restrict__ p_rel, u16* __restrict__ Sv){
  __shared__ float Ash[2*HH*DHH*DHH];   // 32 KB
  for(int i=threadIdx.x;i<2*HH*DHH*DHH;i+=256) Ash[i]=a_rel[i];
  __syncthreads();
  const int gid = blockIdx.x*blockDim.x + threadIdx.x;
  const int node = gid >> 6;
  const int lane = threadIdx.x & 63;
  if(node >= NN) return;
  const int h = lane >> 4, dloc = (lane&15)*2;
  const float2 qv = *(const float2*)&q[(size_t)node*DD + 2*lane];
  // fold a_rel into q: qt[t][j] = sum_e q[h*32+e] * a_rel[t][h][dloc+j][e]
  // (lg = sum_e q[e]*kt[e], kt[e] = sum_d k[d]*A[d][e]  =>  lg = sum_d k[d]*(sum_e q[e]A[d][e]))
  float qt[2][2] = {{0.f,0.f},{0.f,0.f}};
  const int srcbase = lane & 48;
  #pragma unroll
  for(int e=0; e<DHH; ++e){
    const float qe = (e&1) ? __shfl(qv.y, srcbase+(e>>1)) : __shfl(qv.x, srcbase+(e>>1));
    #pragma unroll
    for(int t=0;t<2;++t){
      const float* ar = &Ash[(((t*HH+h)*DHH + dloc)*DHH) + e];
      qt[t][0] = fmaf(qe, ar[0],   qt[t][0]);
      qt[t][1] = fmaf(qe, ar[DHH], qt[t][1]);
    }
  }
  float acc[2][2] = {{0.f,0.f},{0.f,0.f}};
  float ssum = 0.f;
  #pragma unroll
  for(int t=0;t<2;++t){
    const float scale = p_rel[t*HH+h]*0.17677669529663687f;
    const float q0 = qt[t][0], q1 = qt[t][1];
    const int s0 = jrs[t*NN+node], s1 = jrs[t*NN+node+1];
    int p = s0;
    for(; p+3<s1; p+=4){
      const int sA = es[p], sB = es[p+1], sC = es[p+2], sD = es[p+3];
      const u32 kA = *(const u32*)&ktb[(size_t)sA*DD + 2*lane];
      const u32 kB = *(const u32*)&ktb[(size_t)sB*DD + 2*lane];
      const u32 kC = *(const u32*)&ktb[(size_t)sC*DD + 2*lane];
      const u32 kD = *(const u32*)&ktb[(size_t)sD*DD + 2*lane];
      const u32 vA = *(const u32*)&vtb[(size_t)sA*DD + 2*lane];
      const u32 vB = *(const u32*)&vtb[(size_t)sB*DD + 2*lane];
      const u32 vC = *(const u32*)&vtb[(size_t)sC*DD + 2*lane];
      const u32 vD = *(const u32*)&vtb[(size_t)sD*DD + 2*lane];
      float pA = q0*bflo(kA) + q1*bfhi(kA);
      float pB = q0*bflo(kB) + q1*bfhi(kB);
      float pC = q0*bflo(kC) + q1*bfhi(kC);
      float pD = q0*bflo(kD) + q1*bfhi(kD);
      pA += __shfl_xor(pA,1); pB += __shfl_xor(pB,1); pC += __shfl_xor(pC,1); pD += __shfl_xor(pD,1);
      pA += __shfl_xor(pA,2); pB += __shfl_xor(pB,2); pC += __shfl_xor(pC,2); pD += __shfl_xor(pD,2);
      pA += __shfl_xor(pA,4); pB += __shfl_xor(pB,4); pC += __shfl_xor(pC,4); pD += __shfl_xor(pD,4);
      pA += __shfl_xor(pA,8); pB += __shfl_xor(pB,8); pC += __shfl_xor(pC,8); pD += __shfl_xor(pD,8);
      const float eA=__expf(pA*scale), eB=__expf(pB*scale);
      const float eC=__expf(pC*scale), eD=__expf(pD*scale);
      ssum += (eA+eB)+(eC+eD);
      acc[t][0] = fmaf(eA, bflo(vA), acc[t][0]); acc[t][1] = fmaf(eA, bfhi(vA), acc[t][1]);
      acc[t][0] = fmaf(eB, bflo(vB), acc[t][0]); acc[t][1] = fmaf(eB, bfhi(vB), acc[t][1]);
      acc[t][0] = fmaf(eC, bflo(vC), acc[t][0]); acc[t][1] = fmaf(eC, bfhi(vC), acc[t][1]);
      acc[t][0] = fmaf(eD, bflo(vD), acc[t][0]); acc[t][1] = fmaf(eD, bfhi(vD), acc[t][1]);
    }
    for(; p<s1; ++p){
      const int sA = es[p];
      const u32 kA = *(const u32*)&ktb[(size_t)sA*DD + 2*lane];
      const u32 vA = *(const u32*)&vtb[(size_t)sA*DD + 2*lane];
      float pA = q0*bflo(kA) + q1*bfhi(kA);
      pA += __shfl_xor(pA,1); pA += __shfl_xor(pA,2); pA += __shfl_xor(pA,4); pA += __shfl_xor(pA,8);
      const float eA = __expf(pA*scale);
      ssum += eA;
      acc[t][0] = fmaf(eA, bflo(vA), acc[t][0]); acc[t][1] = fmaf(eA, bfhi(vA), acc[t][1]);
    }
  }
  const float inv = ssum>0.f ? 1.f/ssum : 0.f;
  ((u32*)&Sv[(size_t)node*256 +       2*lane])[0] = pack2bf(acc[0][0]*inv, acc[0][1]*inv);
  ((u32*)&Sv[(size_t)node*256 + 128 + 2*lane])[0] = pack2bf(acc[1][0]*inv, acc[1][1]*inv);
}

// ---------------- post-aggregation m_rel transform + gelu ----------------
__global__ __launch_bounds__(256) void mtransform_kernel(const u16* __restrict__ Sv, const float* __restrict__ m_rel,
                                                         float* __restrict__ out){
  __shared__ float Msh[2*HH*DHH*DHH];   // 32 KB
  for(int i=threadIdx.x;i<2*HH*DHH*DHH;i+=256) Msh[i]=m_rel[i];
  __syncthreads();
  int idx = blockIdx.x*blockDim.x + threadIdx.x;
  if(idx >= NN*DD) return;
  int node = idx>>7, f = idx&127, h = f>>5, e = f&31;
  const u16* s0p = &Sv[(size_t)node*256 + h*DHH];
  const u16* s1p = &Sv[(size_t)node*256 + 128 + h*DHH];
  const float* M0 = &Msh[(0*HH+h)*DHH*DHH + e];
  const float* M1 = &Msh[(1*HH+h)*DHH*DHH + e];
  float s = 0.f;
  #pragma unroll
  for(int d=0; d<DHH; d+=2){
    u32 w0 = *(const u32*)&s0p[d];
    u32 w1 = *(const u32*)&s1p[d];
    s = fmaf(bflo(w0), M0[d*DHH],     s);
    s = fmaf(bfhi(w0), M0[(d+1)*DHH], s);
    s = fmaf(bflo(w1), M1[d*DHH],     s);
    s = fmaf(bfhi(w1), M1[(d+1)*DHH], s);
  }
  out[idx] = gelu_exact(s);
}

// ---------------- host ----------------
extern "C" void kernel_launch(void* const* d_in, const int* in_sizes, int n_in,
                              void* d_out, int out_size, void* d_ws, size_t ws_size,
                              hipStream_t stream){
  const float* x_cell = (const float*)d_in[0];
  const float* z_h    = (const float*)d_in[1];
  const float* x_emb  = (const float*)d_in[2];
  const int*   ei0    = (const int*)d_in[3];
  const int*   ei1    = (const int*)d_in[4];
  const float* gat_W  = (const float*)d_in[5];
  const float* gat_as = (const float*)d_in[6];
  const float* gat_ad = (const float*)d_in[7];
  const float* gat_b  = (const float*)d_in[8];
  const float* bn_g   = (const float*)d_in[9];
  const float* bn_b   = (const float*)d_in[10];
  const float* Wk = (const float*)d_in[11];
  const float* bk = (const float*)d_in[12];
  const float* Wq = (const float*)d_in[13];
  const float* bq = (const float*)d_in[14];
  const float* Wv = (const float*)d_in[15];
  const float* bv = (const float*)d_in[16];
  const float* a_rel = (const float*)d_in[17];
  const float* m_rel = (const float*)d_in[18];
  const float* p_rel = (const float*)d_in[19];
  const float* Wo = (const float*)d_in[20];
  const float* bo = (const float*)d_in[21];
  const float* skip = (const float*)d_in[22];
  const float* injW = (const float*)d_in[23];
  const float* injb = (const float*)d_in[24];
  const float* fW1 = (const float*)d_in[25];
  const float* fb1 = (const float*)d_in[26];
  const float* fW2 = (const float*)d_in[27];
  const float* fb2 = (const float*)d_in[28];

  constexpr size_t SLOT = (size_t)NN*DD;   // 6.4M elements
  float* ws = (float*)d_ws;
  float* A    = ws;                       // pre-BN acc / q / mout (f32)
  float* X2   = A + SLOT;                 // x1 then x2 (f32)
  float* als8 = X2 + SLOT;                // NN*8  [node][2*h+t]
  float* ald8 = als8 + (size_t)NN*8;      // NN*8
  float* bnpart = ald8 + (size_t)NN*8;    // 256*256
  float* bnstat = bnpart + 256*256;       // 256
  float* fgb    = bnstat + 256;           // 256
  u16* S    = (u16*)(fgb + 256);          // NN*256 bf16 (HGT Sv)
  u16* XP0  = S + (size_t)NN*256;         // NN*128 bf16 (xp type0 / KTB)
  u16* XP1  = XP0 + SLOT;                 // NN*128 bf16 (xp type1 / VTB)
  u16* es   = XP1 + SLOT;                 // 2*EE u16
  int* jcnt = (int*)(es + (size_t)2*EE + 2);
  int* jrs  = jcnt + N2;                  // N2+1
  int* jcur = jrs + N2 + 2;
  int* bsum = jcur + N2;                  // 256
  int* bofs = bsum + 256;                 // 256
  size_t needed = (size_t)((char*)(bofs + 256) - (char*)d_ws);
  if(ws_size < needed) return;  // insufficient scratch: fail loud (poisoned d_out)

  const int TB = 256;
  dim3 b(TB);
  const int gE2    = (2*EE + TB - 1)/TB;
  const int gND    = (NN*DD + TB - 1)/TB;
  const int gND2   = (NN*64 + TB - 1)/TB;
  const int gNodes = (NN + 3)/4;
  const int gGemm  = (NN + 31)/32;
  const int gScan  = (N2 + 511)/512;

  film_kernel<<<1, 256, 0, stream>>>(z_h, fW1, fb1, fW2, fb2, fgb);

  // joint CSR
  hipMemsetAsync(jcnt, 0, N2*sizeof(int), stream);
  count2_kernel<<<gE2, b, 0, stream>>>(ei0+EE, ei1+EE, jcnt);
  scan_partial<<<gScan, b, 0, stream>>>(jcnt, bsum);
  scan_blocksums<<<1, 256, 0, stream>>>(bsum, bofs, jrs + N2, gScan);
  scan_final<<<gScan, b, 0, stream>>>(jcnt, bofs, jrs, jcur);
  fill2_kernel<<<gE2, b, 0, stream>>>(ei0, ei1, jcur, es);

  // ---- 2 hetero-GAT layers ----
  const float* xin = x_cell;
  for(int c=0;c<2;++c){
    for(int t=0;t<2;++t){
      gemm<GM_ATT|GM_BF16><<<gGemm, b, 0, stream>>>(xin, gat_W + (size_t)(c*2+t)*DD*DD,
          gat_as + (size_t)(c*2+t)*HH*DHH, gat_ad + (size_t)(c*2+t)*HH*DHH,
          nullptr, nullptr, nullptr, als8 + t, ald8 + t, (t? XP1 : XP0), NN);
    }
    gat_gather3<<<gNodes, b, 0, stream>>>(XP0, XP1, als8, ald8, jrs, es,
        gat_b + (size_t)(c*2+0)*DD, gat_b + (size_t)(c*2+1)*DD, A);
    bn_stats<<<256, b, 0, stream>>>(A, bnpart);
    bn_finalize<<<1, 128, 0, stream>>>(bnpart, bn_g + (size_t)c*DD, bn_b + (size_t)c*DD, bnstat, 256);
    bn_apply_lrelu<<<gND2, b, 0, stream>>>(xin, A, bnstat, X2);   // x1 / x2 (in-place safe for c=1)
    xin = X2;
  }
  float* x2 = X2;

  // ---- HGT ----
  gemm<GM_BIAS><<<gGemm, b, 0, stream>>>(x2, Wq, bq, nullptr, nullptr, nullptr, nullptr,
                                         nullptr, nullptr, A, NN);     // q -> A
  gemm<GM_BIAS|GM_BF16><<<gGemm, b, 0, stream>>>(x2, Wk, bk, nullptr, nullptr, nullptr, nullptr,
                                                 nullptr, nullptr, XP0, NN);  // k table
  gemm<GM_BIAS|GM_BF16><<<gGemm, b, 0, stream>>>(x2, Wv, bv, nullptr, nullptr, nullptr, nullptr,
                                                 nullptr, nullptr, XP1, NN);  // v table
  hgt_merged_kernel<<<gNodes, b, 0, stream>>>(A, XP0, XP1, jrs, es, a_rel, p_rel, S);
  mtransform_kernel<<<gND, b, 0, stream>>>(S, m_rel, A);   // gelu(M0^T Sv0 + M1^T Sv1) -> A
  gemm<GM_BIAS|GM_SKIP><<<gGemm, b, 0, stream>>>(A, Wo, bo, nullptr, x2, nullptr, skip,
                                                 nullptr, nullptr, (float*)d_out, NN);
  bn_stats<<<256, b, 0, stream>>>((float*)d_out, bnpart);
  bn_finalize<<<1, 128, 0, stream>>>(bnpart, bn_g + 2*DD, bn_b + 2*DD, bnstat, 256);
  bn_apply_lrelu<<<gND2, b, 0, stream>>>(x2, (float*)d_out, bnstat, (float*)d_out);  // x3c in place
  gemm<GM_BIAS|GM_FILM><<<gGemm, b, 0, stream>>>(x_emb, injW, injb, nullptr, (float*)d_out, fgb, nullptr,
                                                 nullptr, nullptr, (float*)d_out, NN);
}

// Round 7
// 1098.363 us; speedup vs baseline: 1.3154x; 1.3154x over previous
//
#include <hip/hip_runtime.h>
#include <math.h>

#define NN 50000
#define DD 128
#define HH 4
#define DHH 32
#define EE 600000
#define N2 (2*NN)

typedef unsigned short u16;
typedef unsigned int   u32;

__device__ __forceinline__ float lrelu(float v){ return v > 0.f ? v : 0.2f*v; }
__device__ __forceinline__ float gelu_exact(float x){ return 0.5f*x*(1.f+erff(x*0.70710678118654752f)); }
__device__ __forceinline__ u16 f2bf(float f){
  u32 u = __float_as_uint(f);
  u32 r = (u + 0x7fffu + ((u>>16)&1u)) >> 16;
  return (u16)r;
}
__device__ __forceinline__ u32 pack2bf(float a, float b){ return (u32)f2bf(a) | ((u32)f2bf(b)<<16); }
__device__ __forceinline__ float bflo(u32 u){ return __uint_as_float(u<<16); }
__device__ __forceinline__ float bfhi(u32 u){ return __uint_as_float(u & 0xffff0000u); }

// ---------------- FiLM (tiny) ----------------
__global__ void film_kernel(const float* __restrict__ z, const float* __restrict__ W1, const float* __restrict__ b1,
                            const float* __restrict__ W2, const float* __restrict__ b2, float* __restrict__ gb){
  __shared__ float hsh[256];
  int j = threadIdx.x;
  float acc = b1[j];
  for(int d=0; d<DD; ++d) acc = fmaf(z[d], W1[d*256+j], acc);
  hsh[j] = gelu_exact(acc);
  __syncthreads();
  float acc2 = b2[j];
  for(int k=0;k<256;++k) acc2 = fmaf(hsh[k], W2[k*256+j], acc2);
  gb[j] = acc2;
}

// ---------------- fold a_rel into Wq:  wqt[t][c][h*32+m] = sum_e Wq[c][h*32+e]*a_rel[t][h][m][e]
__global__ void fold_qA(const float* __restrict__ Wq, const float* __restrict__ bq,
                        const float* __restrict__ a_rel, float* __restrict__ wqt, float* __restrict__ bqt){
  int idx = blockIdx.x*blockDim.x+threadIdx.x;
  if(idx >= 2*129*128) return;
  int t = idx / (129*128);
  int r = idx % (129*128);
  int c = r >> 7, f = r & 127, h = f>>5, m = f&31;
  const float* srcp = (c<128) ? (Wq + (size_t)c*128 + h*DHH) : (bq + h*DHH);
  const float* arow = a_rel + (((size_t)(t*HH+h)*DHH)+m)*DHH;
  float s=0.f;
  #pragma unroll
  for(int e=0;e<DHH;++e) s = fmaf(srcp[e], arow[e], s);
  if(c<128) wqt[(size_t)t*128*128 + (size_t)c*128 + f] = s;
  else      bqt[t*128 + f] = s;
}

// ---------------- CSR build (joint over both edge types) ----------------
__global__ void count2_kernel(const int* __restrict__ d0, const int* __restrict__ d1, int* __restrict__ jcnt){
  int e = blockIdx.x*blockDim.x+threadIdx.x;
  if(e < EE)        atomicAdd(&jcnt[d0[e]], 1);
  else if(e < 2*EE) atomicAdd(&jcnt[NN + d1[e-EE]], 1);
}

__global__ void scan_partial(const int* __restrict__ cnt, int* __restrict__ bsum){
  int t = threadIdx.x;
  int i0 = blockIdx.x*512 + 2*t;
  int s = 0;
  if(i0   < N2) s += cnt[i0];
  if(i0+1 < N2) s += cnt[i0+1];
  __shared__ int red[256];
  red[t]=s; __syncthreads();
  for(int off=128; off>0; off>>=1){ if(t<off) red[t]+=red[t+off]; __syncthreads(); }
  if(t==0) bsum[blockIdx.x]=red[0];
}

__global__ void scan_blocksums(const int* __restrict__ bsum, int* __restrict__ bofs, int* __restrict__ jrs_last, int nb){
  __shared__ int sh[256];
  int t = threadIdx.x;
  int v = (t<nb)? bsum[t] : 0;
  sh[t]=v; __syncthreads();
  for(int off=1; off<256; off<<=1){
    int u = (t>=off)? sh[t-off] : 0; __syncthreads();
    sh[t]+=u; __syncthreads();
  }
  if(t<nb) bofs[t] = sh[t]-v;
  if(t==nb-1) *jrs_last = sh[t];
}

__global__ void scan_final(const int* __restrict__ cnt, const int* __restrict__ bofs,
                           int* __restrict__ jrs, int* __restrict__ jcur){
  int t = threadIdx.x;
  int i0 = blockIdx.x*512 + 2*t;
  int a = (i0   < N2)? cnt[i0]   : 0;
  int c = (i0+1 < N2)? cnt[i0+1] : 0;
  int s = a+c;
  __shared__ int sh[256];
  sh[t]=s; __syncthreads();
  for(int off=1; off<256; off<<=1){
    int u = (t>=off)? sh[t-off] : 0; __syncthreads();
    sh[t]+=u; __syncthreads();
  }
  int ex = bofs[blockIdx.x] + sh[t]-s;
  if(i0   < N2){ jrs[i0]=ex;     jcur[i0]=ex; }
  if(i0+1 < N2){ jrs[i0+1]=ex+a; jcur[i0+1]=ex+a; }
}

__global__ void fill2_kernel(const int* __restrict__ ei0, const int* __restrict__ ei1,
                             int* __restrict__ jcur, u16* __restrict__ es){
  int e = blockIdx.x*blockDim.x+threadIdx.x;
  if(e < EE){
    int d = ei0[EE+e];
    int pos = atomicAdd(&jcur[d],1);
    es[pos] = (u16)ei0[e];
  } else if(e < 2*EE){
    int i = e-EE;
    int d = ei1[EE+i];
    int pos = atomicAdd(&jcur[NN+d],1);
    es[pos] = (u16)ei1[i];
  }
}

// ---------------- single GEMM (f32 out) + epilogues ----------------
constexpr int GM_BIAS   = 1;
constexpr int GM_FILM   = 4;   // o += base[row,c]; o = fgb[c]*o + fgb[128+c]
constexpr int GM_SKIP   = 16;  // o = sk*o + (1-sk)*base[row,c]

template<int MODE>
__global__ __launch_bounds__(256) void gemm(const float* __restrict__ Av, const float* __restrict__ Wg,
    const float* __restrict__ bias, const float* __restrict__ base, const float* __restrict__ fgb,
    const float* __restrict__ skipv, float* __restrict__ C, int n){
  __shared__ float As[32][128];
  const int tid = threadIdx.x;
  const int row0 = blockIdx.x*32;
  {
    const float4* Ag = (const float4*)(Av + (size_t)row0*DD);
    const int maxv = (min(32, n-row0))*32;
    #pragma unroll
    for(int j=0;j<4;++j){
      int v = tid + j*256;
      float4 val = make_float4(0.f,0.f,0.f,0.f);
      if(v < maxv) val = Ag[v];
      ((float4*)&As[0][0])[v] = val;
    }
  }
  __syncthreads();
  const int c2 = tid & 63;
  const int rh = tid >> 6;
  float acc[8][2];
  #pragma unroll
  for(int r=0;r<8;++r){ acc[r][0]=0.f; acc[r][1]=0.f; }
  #pragma unroll 8
  for(int k=0;k<128;++k){
    const float2 w = *(const float2*)&Wg[(size_t)k*128 + 2*c2];
    #pragma unroll
    for(int r=0;r<8;++r){
      const float a = As[rh*8+r][k];
      acc[r][0] = fmaf(a, w.x, acc[r][0]);
      acc[r][1] = fmaf(a, w.y, acc[r][1]);
    }
  }
  const int c = 2*c2;
  float b0=0.f, b1=0.f;
  if(MODE & GM_BIAS){ b0 = bias[c]; b1 = bias[c+1]; }
  float sk = 0.f;
  if(MODE & GM_SKIP) sk = 1.f/(1.f+__expf(-skipv[0]));
  #pragma unroll
  for(int r=0;r<8;++r){
    int row = row0 + rh*8 + r;
    if(row < n){
      float o0 = acc[r][0]+b0, o1 = acc[r][1]+b1;
      if(MODE & GM_SKIP){
        o0 = sk*o0 + (1.f-sk)*base[(size_t)row*DD + c];
        o1 = sk*o1 + (1.f-sk)*base[(size_t)row*DD + c + 1];
      }
      if(MODE & GM_FILM){
        o0 += base[(size_t)row*DD + c];
        o1 += base[(size_t)row*DD + c + 1];
        o0 = fgb[c]*o0 + fgb[128+c];
        o1 = fgb[c+1]*o1 + fgb[128+c+1];
      }
      C[(size_t)row*DD + c]   = o0;
      C[(size_t)row*DD + c+1] = o1;
    }
  }
}

// ---------------- dual GEMM: one A-tile, two weight mats, bf16/interleaved-KV outputs ----------------
constexpr int G2_BIAS = 1;
constexpr int G2_ATT  = 2;   // GAT logits epilogue for both types -> als8/ald8 [row*8 + 2h + t]
constexpr int G2_KV   = 4;   // interleaved uint2 {kpair, vpair} into Cv0

template<int MODE>
__global__ __launch_bounds__(256) void gemm2(const float* __restrict__ Av,
    const float* __restrict__ Wg0, const float* __restrict__ Wg1,
    const float* __restrict__ bias0, const float* __restrict__ bias1,
    const float* __restrict__ as0, const float* __restrict__ ad0,
    const float* __restrict__ as1, const float* __restrict__ ad1,
    float* __restrict__ als8, float* __restrict__ ald8,
    void* __restrict__ Cv0, void* __restrict__ Cv1, int n){
  __shared__ float As[32][128];
  const int tid = threadIdx.x;
  const int row0 = blockIdx.x*32;
  {
    const float4* Ag = (const float4*)(Av + (size_t)row0*DD);
    const int maxv = (min(32, n-row0))*32;
    #pragma unroll
    for(int j=0;j<4;++j){
      int v = tid + j*256;
      float4 val = make_float4(0.f,0.f,0.f,0.f);
      if(v < maxv) val = Ag[v];
      ((float4*)&As[0][0])[v] = val;
    }
  }
  __syncthreads();
  const int c2 = tid & 63;
  const int rh = tid >> 6;
  float a0[8][2], a1[8][2];
  #pragma unroll
  for(int r=0;r<8;++r){ a0[r][0]=0.f; a0[r][1]=0.f; a1[r][0]=0.f; a1[r][1]=0.f; }
  #pragma unroll 4
  for(int k=0;k<128;++k){
    const float2 w0 = *(const float2*)&Wg0[(size_t)k*128 + 2*c2];
    const float2 w1 = *(const float2*)&Wg1[(size_t)k*128 + 2*c2];
    #pragma unroll
    for(int r=0;r<8;++r){
      const float a = As[rh*8+r][k];
      a0[r][0] = fmaf(a, w0.x, a0[r][0]); a0[r][1] = fmaf(a, w0.y, a0[r][1]);
      a1[r][0] = fmaf(a, w1.x, a1[r][0]); a1[r][1] = fmaf(a, w1.y, a1[r][1]);
    }
  }
  const int c = 2*c2;
  if(MODE & G2_ATT){
    const float2 s0v = *(const float2*)&as0[c], d0v = *(const float2*)&ad0[c];
    const float2 s1v = *(const float2*)&as1[c], d1v = *(const float2*)&ad1[c];
    const int h = c2 >> 4;
    #pragma unroll
    for(int r=0;r<8;++r){
      float ps0 = s0v.x*a0[r][0] + s0v.y*a0[r][1];
      float pd0 = d0v.x*a0[r][0] + d0v.y*a0[r][1];
      float ps1 = s1v.x*a1[r][0] + s1v.y*a1[r][1];
      float pd1 = d1v.x*a1[r][0] + d1v.y*a1[r][1];
      ps0 += __shfl_xor(ps0,1); ps0 += __shfl_xor(ps0,2); ps0 += __shfl_xor(ps0,4); ps0 += __shfl_xor(ps0,8);
      pd0 += __shfl_xor(pd0,1); pd0 += __shfl_xor(pd0,2); pd0 += __shfl_xor(pd0,4); pd0 += __shfl_xor(pd0,8);
      ps1 += __shfl_xor(ps1,1); ps1 += __shfl_xor(ps1,2); ps1 += __shfl_xor(ps1,4); ps1 += __shfl_xor(ps1,8);
      pd1 += __shfl_xor(pd1,1); pd1 += __shfl_xor(pd1,2); pd1 += __shfl_xor(pd1,4); pd1 += __shfl_xor(pd1,8);
      const int row = row0 + rh*8 + r;
      if(row < n && (tid&15)==0){
        als8[(size_t)row*8 + 2*h    ] = ps0;  ald8[(size_t)row*8 + 2*h    ] = pd0;
        als8[(size_t)row*8 + 2*h + 1] = ps1;  ald8[(size_t)row*8 + 2*h + 1] = pd1;
      }
    }
  }
  float b00=0.f,b01=0.f,b10=0.f,b11=0.f;
  if(MODE & G2_BIAS){ b00=bias0[c]; b01=bias0[c+1]; b10=bias1[c]; b11=bias1[c+1]; }
  #pragma unroll
  for(int r=0;r<8;++r){
    int row = row0 + rh*8 + r;
    if(row < n){
      float o00 = a0[r][0]+b00, o01 = a0[r][1]+b01;
      float o10 = a1[r][0]+b10, o11 = a1[r][1]+b11;
      if(MODE & G2_KV){
        uint2 st; st.x = pack2bf(o00,o01); st.y = pack2bf(o10,o11);
        ((uint2*)Cv0)[(size_t)row*64 + c2] = st;
      } else {
        ((u32*)Cv0)[(size_t)row*64 + c2] = pack2bf(o00,o01);
        ((u32*)Cv1)[(size_t)row*64 + c2] = pack2bf(o10,o11);
      }
    }
  }
}

// ---------------- GAT merged gather: both types, per-type xp tables ----------------
__global__ __launch_bounds__(256) void gat_gather3(const u16* __restrict__ xp0, const u16* __restrict__ xp1,
    const float* __restrict__ als8, const float* __restrict__ ald8,
    const int* __restrict__ jrs, const u16* __restrict__ es,
    const float* __restrict__ gb0, const float* __restrict__ gb1, float* __restrict__ out){
  const int gid = blockIdx.x*blockDim.x + threadIdx.x;
  const int node = gid >> 6;
  const int lane = threadIdx.x & 63;
  if(node >= NN) return;
  const int h = lane >> 4;
  const int cc = 2*lane;
  float o0 = gb0[cc] + gb1[cc], o1 = gb0[cc+1] + gb1[cc+1];
  #pragma unroll
  for(int t=0;t<2;++t){
    const u16* __restrict__ xp = t ? xp1 : xp0;
    const float aldv = ald8[(size_t)node*8 + 2*h + t];
    const int s0 = jrs[t*NN+node], s1 = jrs[t*NN+node+1];
    float ssum=0.f, a0=0.f, a1=0.f;
    int p = s0;
    for(; p+3<s1; p+=4){
      const int sA = es[p], sB = es[p+1], sC = es[p+2], sD = es[p+3];
      const u32 xA = *(const u32*)&xp[(size_t)sA*DD + cc];
      const u32 xB = *(const u32*)&xp[(size_t)sB*DD + cc];
      const u32 xC = *(const u32*)&xp[(size_t)sC*DD + cc];
      const u32 xD = *(const u32*)&xp[(size_t)sD*DD + cc];
      float lA = als8[(size_t)sA*8 + 2*h + t] + aldv; lA = lA>0.f? lA : 0.2f*lA;
      float lB = als8[(size_t)sB*8 + 2*h + t] + aldv; lB = lB>0.f? lB : 0.2f*lB;
      float lC = als8[(size_t)sC*8 + 2*h + t] + aldv; lC = lC>0.f? lC : 0.2f*lC;
      float lD = als8[(size_t)sD*8 + 2*h + t] + aldv; lD = lD>0.f? lD : 0.2f*lD;
      const float eA=__expf(lA), eB=__expf(lB), eC=__expf(lC), eD=__expf(lD);
      ssum += (eA+eB)+(eC+eD);
      a0 = fmaf(eA, bflo(xA), a0); a1 = fmaf(eA, bfhi(xA), a1);
      a0 = fmaf(eB, bflo(xB), a0); a1 = fmaf(eB, bfhi(xB), a1);
      a0 = fmaf(eC, bflo(xC), a0); a1 = fmaf(eC, bfhi(xC), a1);
      a0 = fmaf(eD, bflo(xD), a0); a1 = fmaf(eD, bfhi(xD), a1);
    }
    for(; p<s1; ++p){
      const int sA = es[p];
      const u32 xA = *(const u32*)&xp[(size_t)sA*DD + cc];
      float lA = als8[(size_t)sA*8 + 2*h + t] + aldv; lA = lA>0.f? lA : 0.2f*lA;
      const float eA = __expf(lA);
      ssum += eA;
      a0 = fmaf(eA, bflo(xA), a0); a1 = fmaf(eA, bfhi(xA), a1);
    }
    { // self loop (appended in reference)
      float lg = als8[(size_t)node*8 + 2*h + t] + aldv;
      lg = lg>0.f? lg : 0.2f*lg;
      const float ev = __expf(lg);
      ssum += ev;
      const u32 xr = *(const u32*)&xp[(size_t)node*DD + cc];
      a0 = fmaf(ev, bflo(xr), a0); a1 = fmaf(ev, bfhi(xr), a1);
    }
    const float inv = 1.f/ssum;
    o0 = fmaf(a0, inv, o0); o1 = fmaf(a1, inv, o1);
  }
  *(float2*)&out[(size_t)node*DD + cc] = make_float2(o0, o1);
}

// ---------------- BN (deterministic two-stage) ----------------
__global__ void bn_stats(const float* __restrict__ X, float* __restrict__ part){
  int f = threadIdx.x & 127, rg = threadIdx.x>>7;
  float s=0.f, s2=0.f;
  for(int r = blockIdx.x*2+rg; r<NN; r += gridDim.x*2){
    float v = X[(size_t)r*DD+f]; s+=v; s2 = fmaf(v,v,s2);
  }
  __shared__ float ls[256], ls2[256];
  ls[threadIdx.x]=s; ls2[threadIdx.x]=s2; __syncthreads();
  if(rg==0){
    part[blockIdx.x*256 + f]       = ls[f]+ls[128+f];
    part[blockIdx.x*256 + 128 + f] = ls2[f]+ls2[128+f];
  }
}

__global__ void bn_finalize(const float* __restrict__ part, const float* __restrict__ gamma,
                            const float* __restrict__ beta, float* __restrict__ stat, int nblk){
  int f=threadIdx.x;
  float s=0.f, s2=0.f;
  for(int b=0;b<nblk;++b){ s+=part[b*256+f]; s2+=part[b*256+128+f]; }
  float mu = s/(float)NN;
  float var = s2/(float)NN - mu*mu;
  float rs = rsqrtf(var+1e-5f);
  stat[f]     = gamma[f]*rs;
  stat[128+f] = beta[f] - gamma[f]*rs*mu;
}

// out = lrelu(xprev + A*acc + B)
__global__ void bn_apply_lrelu(const float* __restrict__ xprev, const float* __restrict__ acc,
                               const float* __restrict__ stat, float* __restrict__ out){
  int idx = blockIdx.x*blockDim.x+threadIdx.x;
  if(idx >= NN*64) return;
  int c = (2*idx) & 127;
  float2 x = ((const float2*)xprev)[idx];
  float2 a = ((const float2*)acc)[idx];
  float o0 = lrelu(x.x + fmaf(stat[c],   a.x, stat[128+c]));
  float o1 = lrelu(x.y + fmaf(stat[c+1], a.y, stat[128+c+1]));
  ((float2*)out)[idx] = make_float2(o0,o1);
}

// ---------------- HGT merged edge kernel: qt tables + interleaved KV ----------------
__global__ __launch_bounds__(256) void hgt_merged2(const u16* __restrict__ qt,
    const u32* __restrict__ kv, const int* __restrict__ jrs, const u16* __restrict__ es,
    const float* __restrict__ p_rel, u16* __restrict__ Sv){
  const int gid = blockIdx.x*blockDim.x + threadIdx.x;
  const int node = gid >> 6;
  const int lane = threadIdx.x & 63;
  if(node >= NN) return;
  const int h = lane >> 4;
  float acc[2][2] = {{0.f,0.f},{0.f,0.f}};
  float ssum = 0.f;
  #pragma unroll
  for(int t=0;t<2;++t){
    const u32 qw = *(const u32*)&qt[(size_t)t*NN*DD + (size_t)node*DD + 2*lane];
    const float q0 = bflo(qw), q1 = bfhi(qw);
    const float scale = p_rel[t*HH+h]*0.17677669529663687f;
    const int s0 = jrs[t*NN+node], s1 = jrs[t*NN+node+1];
    int p = s0;
    for(; p+3<s1; p+=4){
      const int sA = es[p], sB = es[p+1], sC = es[p+2], sD = es[p+3];
      const uint2 kA = *(const uint2*)&kv[(size_t)sA*128 + 2*lane];
      const uint2 kB = *(const uint2*)&kv[(size_t)sB*128 + 2*lane];
      const uint2 kC = *(const uint2*)&kv[(size_t)sC*128 + 2*lane];
      const uint2 kD = *(const uint2*)&kv[(size_t)sD*128 + 2*lane];
      float pA = q0*bflo(kA.x) + q1*bfhi(kA.x);
      float pB = q0*bflo(kB.x) + q1*bfhi(kB.x);
      float pC = q0*bflo(kC.x) + q1*bfhi(kC.x);
      float pD = q0*bflo(kD.x) + q1*bfhi(kD.x);
      pA += __shfl_xor(pA,1); pB += __shfl_xor(pB,1); pC += __shfl_xor(pC,1); pD += __shfl_xor(pD,1);
      pA += __shfl_xor(pA,2); pB += __shfl_xor(pB,2); pC += __shfl_xor(pC,2); pD += __shfl_xor(pD,2);
      pA += __shfl_xor(pA,4); pB += __shfl_xor(pB,4); pC += __shfl_xor(pC,4); pD += __shfl_xor(pD,4);
      pA += __shfl_xor(pA,8); pB += __shfl_xor(pB,8); pC += __shfl_xor(pC,8); pD += __shfl_xor(pD,8);
      const float eA=__expf(pA*scale), eB=__expf(pB*scale);
      const float eC=__expf(pC*scale), eD=__expf(pD*scale);
      ssum += (eA+eB)+(eC+eD);
      acc[t][0] = fmaf(eA, bflo(kA.y), acc[t][0]); acc[t][1] = fmaf(eA, bfhi(kA.y), acc[t][1]);
      acc[t][0] = fmaf(eB, bflo(kB.y), acc[t][0]); acc[t][1] = fmaf(eB, bfhi(kB.y), acc[t][1]);
      acc[t][0] = fmaf(eC, bflo(kC.y), acc[t][0]); acc[t][1] = fmaf(eC, bfhi(kC.y), acc[t][1]);
      acc[t][0] = fmaf(eD, bflo(kD.y), acc[t][0]); acc[t][1] = fmaf(eD, bfhi(kD.y), acc[t][1]);
    }
    for(; p<s1; ++p){
      const int sA = es[p];
      const uint2 kA = *(const uint2*)&kv[(size_t)sA*128 + 2*lane];
      float pA = q0*bflo(kA.x) + q1*bfhi(kA.x);
      pA += __shfl_xor(pA,1); pA += __shfl_xor(pA,2); pA += __shfl_xor(pA,4); pA += __shfl_xor(pA,8);
      const float eA = __expf(pA*scale);
      ssum += eA;
      acc[t][0] = fmaf(eA, bflo(kA.y), acc[t][0]); acc[t][1] = fmaf(eA, bfhi(kA.y), acc[t][1]);
    }
  }
  const float inv = ssum>0.f ? 1.f/ssum : 0.f;
  ((u32*)&Sv[(size_t)node*256 +       2*lane])[0] = pack2bf(acc[0][0]*inv, acc[0][1]*inv);
  ((u32*)&Sv[(size_t)node*256 + 128 + 2*lane])[0] = pack2bf(acc[1][0]*inv, acc[1][1]*inv);
}

// ---------------- post-aggregation m_rel transform + gelu ----------------
__global__ __launch_bounds__(256) void mtransform_kernel(const u16* __restrict__ Sv, const float* __restrict__ m_rel,
                                                         float* __restrict__ out){
  __shared__ float Msh[2*HH*DHH*DHH];   // 32 KB
  for(int i=threadIdx.x;i<2*HH*DHH*DHH;i+=256) Msh[i]=m_rel[i];
  __syncthreads();
  int idx = blockIdx.x*blockDim.x + threadIdx.x;
  if(idx >= NN*DD) return;
  int node = idx>>7, f = idx&127, h = f>>5, e = f&31;
  const u16* s0p = &Sv[(size_t)node*256 + h*DHH];
  const u16* s1p = &Sv[(size_t)node*256 + 128 + h*DHH];
  const float* M0 = &Msh[(0*HH+h)*DHH*DHH + e];
  const float* M1 = &Msh[(1*HH+h)*DHH*DHH + e];
  float s = 0.f;
  #pragma unroll
  for(int d=0; d<DHH; d+=2){
    u32 w0 = *(const u32*)&s0p[d];
    u32 w1 = *(const u32*)&s1p[d];
    s = fmaf(bflo(w0), M0[d*DHH],     s);
    s = fmaf(bfhi(w0), M0[(d+1)*DHH], s);
    s = fmaf(bflo(w1), M1[d*DHH],     s);
    s = fmaf(bfhi(w1), M1[(d+1)*DHH], s);
  }
  out[idx] = gelu_exact(s);
}

// ---------------- host ----------------
extern "C" void kernel_launch(void* const* d_in, const int* in_sizes, int n_in,
                              void* d_out, int out_size, void* d_ws, size_t ws_size,
                              hipStream_t stream){
  const float* x_cell = (const float*)d_in[0];
  const float* z_h    = (const float*)d_in[1];
  const float* x_emb  = (const float*)d_in[2];
  const int*   ei0    = (const int*)d_in[3];
  const int*   ei1    = (const int*)d_in[4];
  const float* gat_W  = (const float*)d_in[5];
  const float* gat_as = (const float*)d_in[6];
  const float* gat_ad = (const float*)d_in[7];
  const float* gat_b  = (const float*)d_in[8];
  const float* bn_g   = (const float*)d_in[9];
  const float* bn_b   = (const float*)d_in[10];
  const float* Wk = (const float*)d_in[11];
  const float* bk = (const float*)d_in[12];
  const float* Wq = (const float*)d_in[13];
  const float* bq = (const float*)d_in[14];
  const float* Wv = (const float*)d_in[15];
  const float* bv = (const float*)d_in[16];
  const float* a_rel = (const float*)d_in[17];
  const float* m_rel = (const float*)d_in[18];
  const float* p_rel = (const float*)d_in[19];
  const float* Wo = (const float*)d_in[20];
  const float* bo = (const float*)d_in[21];
  const float* skip = (const float*)d_in[22];
  const float* injW = (const float*)d_in[23];
  const float* injb = (const float*)d_in[24];
  const float* fW1 = (const float*)d_in[25];
  const float* fb1 = (const float*)d_in[26];
  const float* fW2 = (const float*)d_in[27];
  const float* fb2 = (const float*)d_in[28];

  constexpr size_t SLOT = (size_t)NN*DD;   // 6.4M elements
  float* ws = (float*)d_ws;
  float* A    = ws;                       // pre-BN acc / QT tables (bf16 x2) / mout (f32)
  float* X2   = A + SLOT;                 // x1 then x2 (f32)
  float* als8 = X2 + SLOT;                // NN*8  [node][2*h+t]
  float* ald8 = als8 + (size_t)NN*8;      // NN*8
  float* bnpart = ald8 + (size_t)NN*8;    // 256*256
  float* bnstat = bnpart + 256*256;       // 256
  float* fgb    = bnstat + 256;           // 256
  float* wqt    = fgb + 256;              // 2*128*128
  float* bqt    = wqt + 2*128*128;        // 2*128
  u16* S    = (u16*)(bqt + 2*128);        // NN*256 bf16 (HGT Sv)
  u16* XP0  = S + (size_t)NN*256;         // NN*128 bf16 (xp type0) ; KV aliases XP0..XP1
  u16* XP1  = XP0 + SLOT;                 // NN*128 bf16 (xp type1)
  u16* es   = XP1 + SLOT;                 // 2*EE u16
  int* jcnt = (int*)(es + (size_t)2*EE + 2);
  int* jrs  = jcnt + N2;                  // N2+1
  int* jcur = jrs + N2 + 2;
  int* bsum = jcur + N2;                  // 256
  int* bofs = bsum + 256;                 // 256
  size_t needed = (size_t)((char*)(bofs + 256) - (char*)d_ws);
  if(ws_size < needed) return;  // insufficient scratch: fail loud (poisoned d_out)

  u16* QT = (u16*)A;            // 2 bf16 qt tables alias the A slot during HGT edge phase
  u32* KV = (u32*)XP0;          // interleaved k/v table aliases XP0+XP1

  const int TB = 256;
  dim3 b(TB);
  const int gE2    = (2*EE + TB - 1)/TB;
  const int gND    = (NN*DD + TB - 1)/TB;
  const int gND2   = (NN*64 + TB - 1)/TB;
  const int gNodes = (NN + 3)/4;
  const int gGemm  = (NN + 31)/32;
  const int gScan  = (N2 + 511)/512;

  film_kernel<<<1, 256, 0, stream>>>(z_h, fW1, fb1, fW2, fb2, fgb);

  // joint CSR
  hipMemsetAsync(jcnt, 0, N2*sizeof(int), stream);
  count2_kernel<<<gE2, b, 0, stream>>>(ei0+EE, ei1+EE, jcnt);
  scan_partial<<<gScan, b, 0, stream>>>(jcnt, bsum);
  scan_blocksums<<<1, 256, 0, stream>>>(bsum, bofs, jrs + N2, gScan);
  scan_final<<<gScan, b, 0, stream>>>(jcnt, bofs, jrs, jcur);
  fill2_kernel<<<gE2, b, 0, stream>>>(ei0, ei1, jcur, es);

  // ---- 2 hetero-GAT layers ----
  const float* xin = x_cell;
  for(int c=0;c<2;++c){
    gemm2<G2_ATT><<<gGemm, b, 0, stream>>>(xin,
        gat_W + (size_t)(c*2+0)*DD*DD, gat_W + (size_t)(c*2+1)*DD*DD,
        nullptr, nullptr,
        gat_as + (size_t)(c*2+0)*HH*DHH, gat_ad + (size_t)(c*2+0)*HH*DHH,
        gat_as + (size_t)(c*2+1)*HH*DHH, gat_ad + (size_t)(c*2+1)*HH*DHH,
        als8, ald8, XP0, XP1, NN);
    gat_gather3<<<gNodes, b, 0, stream>>>(XP0, XP1, als8, ald8, jrs, es,
        gat_b + (size_t)(c*2+0)*DD, gat_b + (size_t)(c*2+1)*DD, A);
    bn_stats<<<256, b, 0, stream>>>(A, bnpart);
    bn_finalize<<<1, 128, 0, stream>>>(bnpart, bn_g + (size_t)c*DD, bn_b + (size_t)c*DD, bnstat, 256);
    bn_apply_lrelu<<<gND2, b, 0, stream>>>(xin, A, bnstat, X2);   // x1 / x2
    xin = X2;
  }
  float* x2 = X2;

  // ---- HGT ----
  fold_qA<<<(2*129*128 + TB-1)/TB, b, 0, stream>>>(Wq, bq, a_rel, wqt, bqt);
  gemm2<G2_BIAS><<<gGemm, b, 0, stream>>>(x2, wqt, wqt + 128*128, bqt, bqt + 128,
      nullptr, nullptr, nullptr, nullptr, nullptr, nullptr, QT, QT + SLOT, NN);     // qt tables
  gemm2<G2_BIAS|G2_KV><<<gGemm, b, 0, stream>>>(x2, Wk, Wv, bk, bv,
      nullptr, nullptr, nullptr, nullptr, nullptr, nullptr, KV, nullptr, NN);       // interleaved k/v
  hgt_merged2<<<gNodes, b, 0, stream>>>(QT, KV, jrs, es, p_rel, S);
  mtransform_kernel<<<gND, b, 0, stream>>>(S, m_rel, A);   // gelu(M0^T Sv0 + M1^T Sv1) -> A (QT dead)
  gemm<GM_BIAS|GM_SKIP><<<gGemm, b, 0, stream>>>(A, Wo, bo, x2, nullptr, skip, (float*)d_out, NN);
  bn_stats<<<256, b, 0, stream>>>((float*)d_out, bnpart);
  bn_finalize<<<1, 128, 0, stream>>>(bnpart, bn_g + 2*DD, bn_b + 2*DD, bnstat, 256);
  bn_apply_lrelu<<<gND2, b, 0, stream>>>(x2, (float*)d_out, bnstat, (float*)d_out);  // x3c in place
  gemm<GM_BIAS|GM_FILM><<<gGemm, b, 0, stream>>>(x_emb, injW, injb, (float*)d_out, fgb, nullptr,
                                                 (float*)d_out, NN);
}

// Round 8
// 932.689 us; speedup vs baseline: 1.5491x; 1.1776x over previous
//
#include <hip/hip_runtime.h>
#include <math.h>

#define NN 50000
#define DD 128
#define HH 4
#define DHH 32
#define EE 600000
#define N2 (2*NN)

typedef unsigned short u16;
typedef unsigned int   u32;
using short8 = __attribute__((ext_vector_type(8))) short;   // 8 bf16 = 4 VGPRs (MFMA A/B frag)
using f32x4  = __attribute__((ext_vector_type(4))) float;   // MFMA C/D frag

__device__ __forceinline__ float lrelu(float v){ return v > 0.f ? v : 0.2f*v; }
__device__ __forceinline__ float gelu_exact(float x){ return 0.5f*x*(1.f+erff(x*0.70710678118654752f)); }
__device__ __forceinline__ u16 f2bf(float f){
  u32 u = __float_as_uint(f);
  u32 r = (u + 0x7fffu + ((u>>16)&1u)) >> 16;
  return (u16)r;
}
__device__ __forceinline__ u32 pack2bf(float a, float b){ return (u32)f2bf(a) | ((u32)f2bf(b)<<16); }
__device__ __forceinline__ float bflo(u32 u){ return __uint_as_float(u<<16); }
__device__ __forceinline__ float bfhi(u32 u){ return __uint_as_float(u & 0xffff0000u); }

// ---------------- FiLM (tiny) ----------------
__global__ void film_kernel(const float* __restrict__ z, const float* __restrict__ W1, const float* __restrict__ b1,
                            const float* __restrict__ W2, const float* __restrict__ b2, float* __restrict__ gb){
  __shared__ float hsh[256];
  int j = threadIdx.x;
  float acc = b1[j];
  for(int d=0; d<DD; ++d) acc = fmaf(z[d], W1[d*256+j], acc);
  hsh[j] = gelu_exact(acc);
  __syncthreads();
  float acc2 = b2[j];
  for(int k=0;k<256;++k) acc2 = fmaf(hsh[k], W2[k*256+j], acc2);
  gb[j] = acc2;
}

// ---------------- weight prep: cast+transpose 8 128x128 f32 mats -> bf16 [n][k] ----------------
// order: 0..3 = gat_W[c*2+t], 4=Wk, 5=Wv, 6=Wo, 7=injW
__global__ void prep_weights(const float* __restrict__ gat_W, const float* __restrict__ Wk,
                             const float* __restrict__ Wv, const float* __restrict__ Wo,
                             const float* __restrict__ injW, u16* __restrict__ WT){
  __shared__ float t[32][33];
  const int m = blockIdx.x >> 4, tile = blockIdx.x & 15, tr = tile>>2, tc = tile&3;
  const float* src = (m<4) ? (gat_W + (size_t)m*16384) : (m==4? Wk : m==5? Wv : m==6? Wo : injW);
  const int lr = threadIdx.x>>5, lc = threadIdx.x&31;
  #pragma unroll
  for(int p=0;p<4;++p) t[lr+p*8][lc] = src[(size_t)(tr*32+lr+p*8)*128 + tc*32+lc];
  __syncthreads();
  #pragma unroll
  for(int p=0;p<4;++p)
    WT[(size_t)m*16384 + (size_t)(tc*32+lr+p*8)*128 + tr*32+lc] = f2bf(t[lc][lr+p*8]);
}

// ---------------- fold a_rel into Wq, output TRANSPOSED bf16 [f][c] ----------------
// wqtT[t][f][c] = sum_e Wq[c][h*32+e]*a_rel[t][h][m][e]  (f = h*32+m); c==128 row is bias (f32)
__global__ void fold_qA(const float* __restrict__ Wq, const float* __restrict__ bq,
                        const float* __restrict__ a_rel, u16* __restrict__ wqtT, float* __restrict__ bqt){
  int idx = blockIdx.x*blockDim.x+threadIdx.x;
  if(idx >= 2*128*129) return;
  int t = idx / (128*129);
  int r = idx % (128*129);
  int f = r / 129, c = r % 129;
  int h = f>>5, m = f&31;
  const float* srcp = (c<128) ? (Wq + (size_t)c*128 + h*DHH) : (bq + h*DHH);
  const float* arow = a_rel + (((size_t)(t*HH+h)*DHH)+m)*DHH;
  float s=0.f;
  #pragma unroll
  for(int e=0;e<DHH;++e) s = fmaf(srcp[e], arow[e], s);
  if(c<128) wqtT[(size_t)t*16384 + (size_t)f*128 + c] = f2bf(s);
  else      bqt[t*128 + f] = s;
}

// ---------------- CSR build (joint over both edge types) ----------------
__global__ void count2_kernel(const int* __restrict__ d0, const int* __restrict__ d1, int* __restrict__ jcnt){
  int e = blockIdx.x*blockDim.x+threadIdx.x;
  if(e < EE)        atomicAdd(&jcnt[d0[e]], 1);
  else if(e < 2*EE) atomicAdd(&jcnt[NN + d1[e-EE]], 1);
}

__global__ void scan_partial(const int* __restrict__ cnt, int* __restrict__ bsum){
  int t = threadIdx.x;
  int i0 = blockIdx.x*512 + 2*t;
  int s = 0;
  if(i0   < N2) s += cnt[i0];
  if(i0+1 < N2) s += cnt[i0+1];
  __shared__ int red[256];
  red[t]=s; __syncthreads();
  for(int off=128; off>0; off>>=1){ if(t<off) red[t]+=red[t+off]; __syncthreads(); }
  if(t==0) bsum[blockIdx.x]=red[0];
}

__global__ void scan_blocksums(const int* __restrict__ bsum, int* __restrict__ bofs, int* __restrict__ jrs_last, int nb){
  __shared__ int sh[256];
  int t = threadIdx.x;
  int v = (t<nb)? bsum[t] : 0;
  sh[t]=v; __syncthreads();
  for(int off=1; off<256; off<<=1){
    int u = (t>=off)? sh[t-off] : 0; __syncthreads();
    sh[t]+=u; __syncthreads();
  }
  if(t<nb) bofs[t] = sh[t]-v;
  if(t==nb-1) *jrs_last = sh[t];
}

__global__ void scan_final(const int* __restrict__ cnt, const int* __restrict__ bofs,
                           int* __restrict__ jrs, int* __restrict__ jcur){
  int t = threadIdx.x;
  int i0 = blockIdx.x*512 + 2*t;
  int a = (i0   < N2)? cnt[i0]   : 0;
  int c = (i0+1 < N2)? cnt[i0+1] : 0;
  int s = a+c;
  __shared__ int sh[256];
  sh[t]=s; __syncthreads();
  for(int off=1; off<256; off<<=1){
    int u = (t>=off)? sh[t-off] : 0; __syncthreads();
    sh[t]+=u; __syncthreads();
  }
  int ex = bofs[blockIdx.x] + sh[t]-s;
  if(i0   < N2){ jrs[i0]=ex;     jcur[i0]=ex; }
  if(i0+1 < N2){ jrs[i0+1]=ex+a; jcur[i0+1]=ex+a; }
}

__global__ void fill2_kernel(const int* __restrict__ ei0, const int* __restrict__ ei1,
                             int* __restrict__ jcur, u16* __restrict__ es){
  int e = blockIdx.x*blockDim.x+threadIdx.x;
  if(e < EE){
    int d = ei0[EE+e];
    int pos = atomicAdd(&jcur[d],1);
    es[pos] = (u16)ei0[e];
  } else if(e < 2*EE){
    int i = e-EE;
    int d = ei1[EE+i];
    int pos = atomicAdd(&jcur[NN+d],1);
    es[pos] = (u16)ei1[i];
  }
}

// ---------------- MFMA GEMM: C[n,128] = A[n,128](f32->bf16) @ W[128,128] (WT bf16 [n][k]) ----------------
constexpr int MM_BIAS = 1;
constexpr int MM_FILM = 2;   // o += base[row,c]; o = fgb[c]*o + fgb[128+c]
constexpr int MM_SKIP = 4;   // o = sk*o + (1-sk)*base[row,c]
constexpr int MM_ATT  = 8;   // GAT logits -> als8/ald8 at [row*8 + 2h + att_t]
constexpr int MM_BF16 = 16;  // bf16 output table
constexpr int MM_KV   = 32;  // interleaved kv table, kvpart selects k(0)/v(1) slot

#define SWZ(row, byte) ((byte) ^ (((row)&7)<<4))

template<int MODE>
__global__ __launch_bounds__(256) void mgemm(const float* __restrict__ Av, const u16* __restrict__ WT,
    const float* __restrict__ bias, const float* __restrict__ base, const float* __restrict__ fgb,
    const float* __restrict__ skipv, const float* __restrict__ as_, const float* __restrict__ ad_,
    float* __restrict__ als8, float* __restrict__ ald8, int att_t,
    void* __restrict__ Cv, int kvpart, int n){
  __shared__ u16 Al[64*128];    // 16 KB, swizzled rows
  __shared__ u16 Wl[128*128];   // 32 KB, swizzled rows (WT is [n][k])
  const int tid = threadIdx.x;
  const int row0 = blockIdx.x*64;
  { // stage A (f32 -> bf16)
    const float4* Ag = (const float4*)(Av + (size_t)row0*128);
    const int maxv = (min(64, n-row0))*32;
    #pragma unroll
    for(int j=0;j<8;++j){
      int v = tid + j*256;                 // float4 index: row = v>>5, col4 = v&31
      float4 val = make_float4(0.f,0.f,0.f,0.f);
      if(v < maxv) val = Ag[v];
      int row = v>>5, cb = (v&31)*8;
      uint2 st; st.x = pack2bf(val.x, val.y); st.y = pack2bf(val.z, val.w);
      *(uint2*)((char*)Al + row*256 + SWZ(row, cb)) = st;
    }
  }
  { // stage WT (bf16 already)
    const u32* Wg = (const u32*)WT;
    #pragma unroll
    for(int j=0;j<32;++j){
      int v = tid + j*256;                 // u32 index: row = v>>6, colpair = v&63
      u32 w = Wg[v];
      int row = v>>6, cb = (v&63)*4;
      *(u32*)((char*)Wl + row*256 + SWZ(row, cb)) = w;
    }
  }
  __syncthreads();
  const int lane = tid & 63;
  const int wv   = tid >> 6;     // wave: rows wv*16..+15
  const int r16  = lane & 15;
  const int kg   = lane >> 4;
  f32x4 acc[8];
  #pragma unroll
  for(int nn=0;nn<8;++nn) acc[nn] = (f32x4){0.f,0.f,0.f,0.f};
  #pragma unroll
  for(int s=0;s<4;++s){
    const int arow = wv*16 + r16;
    const int kb = s*64 + kg*16;
    short8 af = *(const short8*)((const char*)Al + arow*256 + SWZ(arow, kb));
    #pragma unroll
    for(int nn=0;nn<8;++nn){
      const int brow = nn*16 + r16;
      short8 bf = *(const short8*)((const char*)Wl + brow*256 + SWZ(brow, kb));
      acc[nn] = __builtin_amdgcn_mfma_f32_16x16x32_bf16(af, bf, acc[nn], 0, 0, 0);
    }
  }
  // lane holds C[row0 + wv*16 + kg*4 + i][nn*16 + r16] = acc[nn][i]
  if(MODE & MM_ATT){
    float asv[8], adv[8];
    #pragma unroll
    for(int nn=0;nn<8;++nn){ asv[nn]=as_[nn*16+r16]; adv[nn]=ad_[nn*16+r16]; }
    #pragma unroll
    for(int i=0;i<4;++i){
      const int row = row0 + wv*16 + kg*4 + i;
      #pragma unroll
      for(int h=0;h<4;++h){
        float ps = asv[2*h]*acc[2*h][i] + asv[2*h+1]*acc[2*h+1][i];
        float pd = adv[2*h]*acc[2*h][i] + adv[2*h+1]*acc[2*h+1][i];
        ps += __shfl_xor(ps,1); ps += __shfl_xor(ps,2); ps += __shfl_xor(ps,4); ps += __shfl_xor(ps,8);
        pd += __shfl_xor(pd,1); pd += __shfl_xor(pd,2); pd += __shfl_xor(pd,4); pd += __shfl_xor(pd,8);
        if(row < n && r16 == 0){
          als8[(size_t)row*8 + 2*h + att_t] = ps;
          ald8[(size_t)row*8 + 2*h + att_t] = pd;
        }
      }
    }
  }
  float bvals[8];
  if(MODE & MM_BIAS){
    #pragma unroll
    for(int nn=0;nn<8;++nn) bvals[nn] = bias[nn*16+r16];
  }
  float sk = 0.f;
  if(MODE & MM_SKIP) sk = 1.f/(1.f+__expf(-skipv[0]));
  #pragma unroll
  for(int i=0;i<4;++i){
    const int row = row0 + wv*16 + kg*4 + i;
    if(row >= n) continue;
    #pragma unroll
    for(int nn=0;nn<8;++nn){
      const int col = nn*16 + r16;
      float o = acc[nn][i];
      if(MODE & MM_BIAS) o += bvals[nn];
      if(MODE & MM_SKIP)
        o = sk*o + (1.f-sk)*base[(size_t)row*128 + col];
      if(MODE & MM_FILM){
        o += base[(size_t)row*128 + col];
        o = fgb[col]*o + fgb[128+col];
      }
      if(MODE & MM_BF16)
        ((u16*)Cv)[(size_t)row*128 + col] = f2bf(o);
      else if(MODE & MM_KV)
        *(u16*)((char*)Cv + (size_t)row*512 + (col>>1)*8 + (col&1)*2 + kvpart*4) = f2bf(o);
      else
        ((float*)Cv)[(size_t)row*128 + col] = o;
    }
  }
}

// ---------------- GAT merged gather: both types, per-type xp tables ----------------
__global__ __launch_bounds__(256) void gat_gather3(const u16* __restrict__ xp0, const u16* __restrict__ xp1,
    const float* __restrict__ als8, const float* __restrict__ ald8,
    const int* __restrict__ jrs, const u16* __restrict__ es,
    const float* __restrict__ gb0, const float* __restrict__ gb1, float* __restrict__ out){
  const int gid = blockIdx.x*blockDim.x + threadIdx.x;
  const int node = gid >> 6;
  const int lane = threadIdx.x & 63;
  if(node >= NN) return;
  const int h = lane >> 4;
  const int cc = 2*lane;
  float o0 = gb0[cc] + gb1[cc], o1 = gb0[cc+1] + gb1[cc+1];
  #pragma unroll
  for(int t=0;t<2;++t){
    const u16* __restrict__ xp = t ? xp1 : xp0;
    const float aldv = ald8[(size_t)node*8 + 2*h + t];
    const int s0 = jrs[t*NN+node], s1 = jrs[t*NN+node+1];
    float ssum=0.f, a0=0.f, a1=0.f;
    int p = s0;
    for(; p+3<s1; p+=4){
      const int sA = es[p], sB = es[p+1], sC = es[p+2], sD = es[p+3];
      const u32 xA = *(const u32*)&xp[(size_t)sA*DD + cc];
      const u32 xB = *(const u32*)&xp[(size_t)sB*DD + cc];
      const u32 xC = *(const u32*)&xp[(size_t)sC*DD + cc];
      const u32 xD = *(const u32*)&xp[(size_t)sD*DD + cc];
      float lA = als8[(size_t)sA*8 + 2*h + t] + aldv; lA = lA>0.f? lA : 0.2f*lA;
      float lB = als8[(size_t)sB*8 + 2*h + t] + aldv; lB = lB>0.f? lB : 0.2f*lB;
      float lC = als8[(size_t)sC*8 + 2*h + t] + aldv; lC = lC>0.f? lC : 0.2f*lC;
      float lD = als8[(size_t)sD*8 + 2*h + t] + aldv; lD = lD>0.f? lD : 0.2f*lD;
      const float eA=__expf(lA), eB=__expf(lB), eC=__expf(lC), eD=__expf(lD);
      ssum += (eA+eB)+(eC+eD);
      a0 = fmaf(eA, bflo(xA), a0); a1 = fmaf(eA, bfhi(xA), a1);
      a0 = fmaf(eB, bflo(xB), a0); a1 = fmaf(eB, bfhi(xB), a1);
      a0 = fmaf(eC, bflo(xC), a0); a1 = fmaf(eC, bfhi(xC), a1);
      a0 = fmaf(eD, bflo(xD), a0); a1 = fmaf(eD, bfhi(xD), a1);
    }
    for(; p<s1; ++p){
      const int sA = es[p];
      const u32 xA = *(const u32*)&xp[(size_t)sA*DD + cc];
      float lA = als8[(size_t)sA*8 + 2*h + t] + aldv; lA = lA>0.f? lA : 0.2f*lA;
      const float eA = __expf(lA);
      ssum += eA;
      a0 = fmaf(eA, bflo(xA), a0); a1 = fmaf(eA, bfhi(xA), a1);
    }
    { // self loop (appended in reference)
      float lg = als8[(size_t)node*8 + 2*h + t] + aldv;
      lg = lg>0.f? lg : 0.2f*lg;
      const float ev = __expf(lg);
      ssum += ev;
      const u32 xr = *(const u32*)&xp[(size_t)node*DD + cc];
      a0 = fmaf(ev, bflo(xr), a0); a1 = fmaf(ev, bfhi(xr), a1);
    }
    const float inv = 1.f/ssum;
    o0 = fmaf(a0, inv, o0); o1 = fmaf(a1, inv, o1);
  }
  *(float2*)&out[(size_t)node*DD + cc] = make_float2(o0, o1);
}

// ---------------- BN (deterministic two-stage) ----------------
__global__ void bn_stats(const float* __restrict__ X, float* __restrict__ part){
  int f = threadIdx.x & 127, rg = threadIdx.x>>7;
  float s=0.f, s2=0.f;
  for(int r = blockIdx.x*2+rg; r<NN; r += gridDim.x*2){
    float v = X[(size_t)r*DD+f]; s+=v; s2 = fmaf(v,v,s2);
  }
  __shared__ float ls[256], ls2[256];
  ls[threadIdx.x]=s; ls2[threadIdx.x]=s2; __syncthreads();
  if(rg==0){
    part[blockIdx.x*256 + f]       = ls[f]+ls[128+f];
    part[blockIdx.x*256 + 128 + f] = ls2[f]+ls2[128+f];
  }
}

__global__ void bn_finalize(const float* __restrict__ part, const float* __restrict__ gamma,
                            const float* __restrict__ beta, float* __restrict__ stat, int nblk){
  int f=threadIdx.x;
  float s=0.f, s2=0.f;
  for(int b=0;b<nblk;++b){ s+=part[b*256+f]; s2+=part[b*256+128+f]; }
  float mu = s/(float)NN;
  float var = s2/(float)NN - mu*mu;
  float rs = rsqrtf(var+1e-5f);
  stat[f]     = gamma[f]*rs;
  stat[128+f] = beta[f] - gamma[f]*rs*mu;
}

// out = lrelu(xprev + A*acc + B)
__global__ void bn_apply_lrelu(const float* __restrict__ xprev, const float* __restrict__ acc,
                               const float* __restrict__ stat, float* __restrict__ out){
  int idx = blockIdx.x*blockDim.x+threadIdx.x;
  if(idx >= NN*64) return;
  int c = (2*idx) & 127;
  float2 x = ((const float2*)xprev)[idx];
  float2 a = ((const float2*)acc)[idx];
  float o0 = lrelu(x.x + fmaf(stat[c],   a.x, stat[128+c]));
  float o1 = lrelu(x.y + fmaf(stat[c+1], a.y, stat[128+c+1]));
  ((float2*)out)[idx] = make_float2(o0,o1);
}

// ---------------- HGT merged edge kernel: qt tables + interleaved KV ----------------
__global__ __launch_bounds__(256) void hgt_merged2(const u16* __restrict__ qt,
    const u32* __restrict__ kv, const int* __restrict__ jrs, const u16* __restrict__ es,
    const float* __restrict__ p_rel, u16* __restrict__ Sv){
  const int gid = blockIdx.x*blockDim.x + threadIdx.x;
  const int node = gid >> 6;
  const int lane = threadIdx.x & 63;
  if(node >= NN) return;
  const int h = lane >> 4;
  float acc[2][2] = {{0.f,0.f},{0.f,0.f}};
  float ssum = 0.f;
  #pragma unroll
  for(int t=0;t<2;++t){
    const u32 qw = *(const u32*)&qt[(size_t)t*NN*DD + (size_t)node*DD + 2*lane];
    const float q0 = bflo(qw), q1 = bfhi(qw);
    const float scale = p_rel[t*HH+h]*0.17677669529663687f;
    const int s0 = jrs[t*NN+node], s1 = jrs[t*NN+node+1];
    int p = s0;
    for(; p+3<s1; p+=4){
      const int sA = es[p], sB = es[p+1], sC = es[p+2], sD = es[p+3];
      const uint2 kA = *(const uint2*)&kv[(size_t)sA*128 + 2*lane];
      const uint2 kB = *(const uint2*)&kv[(size_t)sB*128 + 2*lane];
      const uint2 kC = *(const uint2*)&kv[(size_t)sC*128 + 2*lane];
      const uint2 kD = *(const uint2*)&kv[(size_t)sD*128 + 2*lane];
      float pA = q0*bflo(kA.x) + q1*bfhi(kA.x);
      float pB = q0*bflo(kB.x) + q1*bfhi(kB.x);
      float pC = q0*bflo(kC.x) + q1*bfhi(kC.x);
      float pD = q0*bflo(kD.x) + q1*bfhi(kD.x);
      pA += __shfl_xor(pA,1); pB += __shfl_xor(pB,1); pC += __shfl_xor(pC,1); pD += __shfl_xor(pD,1);
      pA += __shfl_xor(pA,2); pB += __shfl_xor(pB,2); pC += __shfl_xor(pC,2); pD += __shfl_xor(pD,2);
      pA += __shfl_xor(pA,4); pB += __shfl_xor(pB,4); pC += __shfl_xor(pC,4); pD += __shfl_xor(pD,4);
      pA += __shfl_xor(pA,8); pB += __shfl_xor(pB,8); pC += __shfl_xor(pC,8); pD += __shfl_xor(pD,8);
      const float eA=__expf(pA*scale), eB=__expf(pB*scale);
      const float eC=__expf(pC*scale), eD=__expf(pD*scale);
      ssum += (eA+eB)+(eC+eD);
      acc[t][0] = fmaf(eA, bflo(kA.y), acc[t][0]); acc[t][1] = fmaf(eA, bfhi(kA.y), acc[t][1]);
      acc[t][0] = fmaf(eB, bflo(kB.y), acc[t][0]); acc[t][1] = fmaf(eB, bfhi(kB.y), acc[t][1]);
      acc[t][0] = fmaf(eC, bflo(kC.y), acc[t][0]); acc[t][1] = fmaf(eC, bfhi(kC.y), acc[t][1]);
      acc[t][0] = fmaf(eD, bflo(kD.y), acc[t][0]); acc[t][1] = fmaf(eD, bfhi(kD.y), acc[t][1]);
    }
    for(; p<s1; ++p){
      const int sA = es[p];
      const uint2 kA = *(const uint2*)&kv[(size_t)sA*128 + 2*lane];
      float pA = q0*bflo(kA.x) + q1*bfhi(kA.x);
      pA += __shfl_xor(pA,1); pA += __shfl_xor(pA,2); pA += __shfl_xor(pA,4); pA += __shfl_xor(pA,8);
      const float eA = __expf(pA*scale);
      ssum += eA;
      acc[t][0] = fmaf(eA, bflo(kA.y), acc[t][0]); acc[t][1] = fmaf(eA, bfhi(kA.y), acc[t][1]);
    }
  }
  const float inv = ssum>0.f ? 1.f/ssum : 0.f;
  ((u32*)&Sv[(size_t)node*256 +       2*lane])[0] = pack2bf(acc[0][0]*inv, acc[0][1]*inv);
  ((u32*)&Sv[(size_t)node*256 + 128 + 2*lane])[0] = pack2bf(acc[1][0]*inv, acc[1][1]*inv);
}

// ---------------- post-aggregation m_rel transform + gelu ----------------
__global__ __launch_bounds__(256) void mtransform_kernel(const u16* __restrict__ Sv, const float* __restrict__ m_rel,
                                                         float* __restrict__ out){
  __shared__ float Msh[2*HH*DHH*DHH];   // 32 KB
  for(int i=threadIdx.x;i<2*HH*DHH*DHH;i+=256) Msh[i]=m_rel[i];
  __syncthreads();
  int idx = blockIdx.x*blockDim.x + threadIdx.x;
  if(idx >= NN*DD) return;
  int node = idx>>7, f = idx&127, h = f>>5, e = f&31;
  const u16* s0p = &Sv[(size_t)node*256 + h*DHH];
  const u16* s1p = &Sv[(size_t)node*256 + 128 + h*DHH];
  const float* M0 = &Msh[(0*HH+h)*DHH*DHH + e];
  const float* M1 = &Msh[(1*HH+h)*DHH*DHH + e];
  float s = 0.f;
  #pragma unroll
  for(int d=0; d<DHH; d+=2){
    u32 w0 = *(const u32*)&s0p[d];
    u32 w1 = *(const u32*)&s1p[d];
    s = fmaf(bflo(w0), M0[d*DHH],     s);
    s = fmaf(bfhi(w0), M0[(d+1)*DHH], s);
    s = fmaf(bflo(w1), M1[d*DHH],     s);
    s = fmaf(bfhi(w1), M1[(d+1)*DHH], s);
  }
  out[idx] = gelu_exact(s);
}

// ---------------- host ----------------
extern "C" void kernel_launch(void* const* d_in, const int* in_sizes, int n_in,
                              void* d_out, int out_size, void* d_ws, size_t ws_size,
                              hipStream_t stream){
  const float* x_cell = (const float*)d_in[0];
  const float* z_h    = (const float*)d_in[1];
  const float* x_emb  = (const float*)d_in[2];
  const int*   ei0    = (const int*)d_in[3];
  const int*   ei1    = (const int*)d_in[4];
  const float* gat_W  = (const float*)d_in[5];
  const float* gat_as = (const float*)d_in[6];
  const float* gat_ad = (const float*)d_in[7];
  const float* gat_b  = (const float*)d_in[8];
  const float* bn_g   = (const float*)d_in[9];
  const float* bn_b   = (const float*)d_in[10];
  const float* Wk = (const float*)d_in[11];
  const float* bk = (const float*)d_in[12];
  const float* Wq = (const float*)d_in[13];
  const float* bq = (const float*)d_in[14];
  const float* Wv = (const float*)d_in[15];
  const float* bv = (const float*)d_in[16];
  const float* a_rel = (const float*)d_in[17];
  const float* m_rel = (const float*)d_in[18];
  const float* p_rel = (const float*)d_in[19];
  const float* Wo = (const float*)d_in[20];
  const float* bo = (const float*)d_in[21];
  const float* skip = (const float*)d_in[22];
  const float* injW = (const float*)d_in[23];
  const float* injb = (const float*)d_in[24];
  const float* fW1 = (const float*)d_in[25];
  const float* fb1 = (const float*)d_in[26];
  const float* fW2 = (const float*)d_in[27];
  const float* fb2 = (const float*)d_in[28];

  constexpr size_t SLOT = (size_t)NN*DD;   // 6.4M elements
  float* ws = (float*)d_ws;
  float* A    = ws;                       // pre-BN acc / QT tables (bf16 x2) / mout (f32)
  float* X2   = A + SLOT;                 // x1 then x2 (f32)
  float* als8 = X2 + SLOT;                // NN*8  [node][2*h+t]
  float* ald8 = als8 + (size_t)NN*8;      // NN*8
  float* bnpart = ald8 + (size_t)NN*8;    // 256*256
  float* bnstat = bnpart + 256*256;       // 256
  float* fgb    = bnstat + 256;           // 256
  float* bqt    = fgb + 256;              // 2*128
  u16* WT8  = (u16*)(bqt + 2*128);        // 8 * 128*128 bf16 (transposed weights)
  u16* WQT  = WT8 + (size_t)8*16384;      // 2 * 128*128 bf16 (folded q weights, transposed)
  u16* S    = WQT + (size_t)2*16384;      // NN*256 bf16 (HGT Sv)
  u16* XP0  = S + (size_t)NN*256;         // NN*128 bf16 (xp type0) ; KV aliases XP0..XP1
  u16* XP1  = XP0 + SLOT;                 // NN*128 bf16 (xp type1)
  u16* es   = XP1 + SLOT;                 // 2*EE u16
  int* jcnt = (int*)(es + (size_t)2*EE + 2);
  int* jrs  = jcnt + N2;                  // N2+1
  int* jcur = jrs + N2 + 2;
  int* bsum = jcur + N2;                  // 256
  int* bofs = bsum + 256;                 // 256
  size_t needed = (size_t)((char*)(bofs + 256) - (char*)d_ws);
  if(ws_size < needed) return;  // insufficient scratch: fail loud (poisoned d_out)

  u16* QT = (u16*)A;            // 2 bf16 qt tables alias the A slot during HGT edge phase
  u32* KV = (u32*)XP0;          // interleaved k/v table aliases XP0+XP1

  const int TB = 256;
  dim3 b(TB);
  const int gE2    = (2*EE + TB - 1)/TB;
  const int gND    = (NN*DD + TB - 1)/TB;
  const int gND2   = (NN*64 + TB - 1)/TB;
  const int gNodes = (NN + 3)/4;
  const int gMG    = (NN + 63)/64;        // mgemm: 64-row tiles
  const int gScan  = (N2 + 511)/512;

  film_kernel<<<1, 256, 0, stream>>>(z_h, fW1, fb1, fW2, fb2, fgb);
  prep_weights<<<128, b, 0, stream>>>(gat_W, Wk, Wv, Wo, injW, WT8);
  fold_qA<<<(2*128*129 + TB-1)/TB, b, 0, stream>>>(Wq, bq, a_rel, WQT, bqt);

  // joint CSR
  hipMemsetAsync(jcnt, 0, N2*sizeof(int), stream);
  count2_kernel<<<gE2, b, 0, stream>>>(ei0+EE, ei1+EE, jcnt);
  scan_partial<<<gScan, b, 0, stream>>>(jcnt, bsum);
  scan_blocksums<<<1, 256, 0, stream>>>(bsum, bofs, jrs + N2, gScan);
  scan_final<<<gScan, b, 0, stream>>>(jcnt, bofs, jrs, jcur);
  fill2_kernel<<<gE2, b, 0, stream>>>(ei0, ei1, jcur, es);

  // ---- 2 hetero-GAT layers ----
  const float* xin = x_cell;
  for(int c=0;c<2;++c){
    for(int t=0;t<2;++t){
      mgemm<MM_ATT|MM_BF16><<<gMG, b, 0, stream>>>(xin, WT8 + (size_t)(c*2+t)*16384,
          nullptr, nullptr, nullptr, nullptr,
          gat_as + (size_t)(c*2+t)*HH*DHH, gat_ad + (size_t)(c*2+t)*HH*DHH,
          als8, ald8, t, (t? XP1 : XP0), 0, NN);
    }
    gat_gather3<<<gNodes, b, 0, stream>>>(XP0, XP1, als8, ald8, jrs, es,
        gat_b + (size_t)(c*2+0)*DD, gat_b + (size_t)(c*2+1)*DD, A);
    bn_stats<<<256, b, 0, stream>>>(A, bnpart);
    bn_finalize<<<1, 128, 0, stream>>>(bnpart, bn_g + (size_t)c*DD, bn_b + (size_t)c*DD, bnstat, 256);
    bn_apply_lrelu<<<gND2, b, 0, stream>>>(xin, A, bnstat, X2);   // x1 / x2
    xin = X2;
  }
  float* x2 = X2;

  // ---- HGT ----
  for(int t=0;t<2;++t)
    mgemm<MM_BIAS|MM_BF16><<<gMG, b, 0, stream>>>(x2, WQT + (size_t)t*16384, bqt + t*128,
        nullptr, nullptr, nullptr, nullptr, nullptr, nullptr, nullptr, 0, QT + (size_t)t*SLOT, 0, NN);
  mgemm<MM_BIAS|MM_KV><<<gMG, b, 0, stream>>>(x2, WT8 + (size_t)4*16384, bk,
      nullptr, nullptr, nullptr, nullptr, nullptr, nullptr, nullptr, 0, KV, 0, NN);  // k slots
  mgemm<MM_BIAS|MM_KV><<<gMG, b, 0, stream>>>(x2, WT8 + (size_t)5*16384, bv,
      nullptr, nullptr, nullptr, nullptr, nullptr, nullptr, nullptr, 0, KV, 1, NN);  // v slots
  hgt_merged2<<<gNodes, b, 0, stream>>>(QT, KV, jrs, es, p_rel, S);
  mtransform_kernel<<<gND, b, 0, stream>>>(S, m_rel, A);   // gelu(M0^T Sv0 + M1^T Sv1) -> A (QT dead)
  mgemm<MM_BIAS|MM_SKIP><<<gMG, b, 0, stream>>>(A, WT8 + (size_t)6*16384, bo,
      x2, nullptr, skip, nullptr, nullptr, nullptr, nullptr, 0, (float*)d_out, 0, NN);
  bn_stats<<<256, b, 0, stream>>>((float*)d_out, bnpart);
  bn_finalize<<<1, 128, 0, stream>>>(bnpart, bn_g + 2*DD, bn_b + 2*DD, bnstat, 256);
  bn_apply_lrelu<<<gND2, b, 0, stream>>>(x2, (float*)d_out, bnstat, (float*)d_out);  // x3c in place
  mgemm<MM_BIAS|MM_FILM><<<gMG, b, 0, stream>>>(x_emb, WT8 + (size_t)7*16384, injb,
      (float*)d_out, fgb, nullptr, nullptr, nullptr, nullptr, nullptr, 0, (float*)d_out, 0, NN);
}